// Round 9
// baseline (56.628 us; speedup 1.0000x reference)
//
#include <hip/hip_runtime.h>
#include <math.h>

#define BATCH 512
#define DIN   5120
#define DST   16
#define RK    160
#define NJ    192     // 160 dt_rank + 16 B + 16 C
#define NZ1   16      // GEMM1 split-K slices (K=320 each, 10 MFMA steps)

typedef __attribute__((ext_vector_type(8))) __bf16 bf16x8;
typedef __attribute__((ext_vector_type(4))) float f32x4;
typedef __attribute__((ext_vector_type(8))) unsigned short ushort8;

// ws byte offsets (all 16B aligned)
#define OFF_XP    0u          // xP   [640 k8][512 b][8]  bf16
#define OFF_WP    5242880u    // WP   [640 k8][192 j][8]  bf16
#define OFF_WDTP  7208960u    // WdtP [20 k8][5120 d][8]  bf16
#define OFF_PART  8847360u    // part1[6144 task][256]    f32
#define OFF_DTRP  15138816u   // dtrP [20 k8][512 b][8]   bf16
#define OFF_B     15302656u   // Bc   [512][16] f32
#define OFF_C     15335424u   // Cc   [512][16] f32

__device__ __forceinline__ unsigned short f2bf(float f) {
  unsigned int u = __float_as_uint(f);
  u = (u + 0x7FFFu + ((u >> 16) & 1u)) >> 16;   // RNE
  return (unsigned short)u;
}

// ---------------------------------------------------------------------------
// k_prep: pack bf16 operands (xP, WP, WdtP). 2160 blocks.
// ---------------------------------------------------------------------------
#define N1 (512*640)
#define N2 (192*640)
__global__ __launch_bounds__(256) void k_prep(
    const float* __restrict__ x, const float* __restrict__ Wdtr,
    const float* __restrict__ WB, const float* __restrict__ WC,
    const float* __restrict__ Wdt, char* __restrict__ ws)
{
  const int tid = blockIdx.x * 256 + threadIdx.x;
  const float* src; unsigned long long dst_idx;
  if (tid < N1) {
    const int b = tid / 640, k8 = tid - b * 640;
    src = x + (size_t)b * DIN + k8 * 8;
    dst_idx = (OFF_XP >> 4) + (size_t)k8 * 512 + b;
  } else if (tid < N1 + N2) {
    const int i = tid - N1;
    const int j = i / 640, k8 = i - j * 640;
    const float* row;
    if (j < RK)            row = Wdtr + (size_t)j * DIN;
    else if (j < RK + DST) row = WB   + (size_t)(j - RK) * DIN;
    else                   row = WC   + (size_t)(j - RK - DST) * DIN;
    src = row + k8 * 8;
    dst_idx = (OFF_WP >> 4) + (size_t)k8 * 192 + j;
  } else {
    const int i = tid - N1 - N2;          // < 5120*20
    const int d = i / 20, k8 = i - d * 20;
    src = Wdt + (size_t)d * RK + k8 * 8;
    dst_idx = (OFF_WDTP >> 4) + (size_t)k8 * 5120 + d;
  }
  const float4 f0 = *(const float4*)(src);
  const float4 f1 = *(const float4*)(src + 4);
  ushort8 o;
  o[0]=f2bf(f0.x); o[1]=f2bf(f0.y); o[2]=f2bf(f0.z); o[3]=f2bf(f0.w);
  o[4]=f2bf(f1.x); o[5]=f2bf(f1.y); o[6]=f2bf(f1.z); o[7]=f2bf(f1.w);
  ((ushort8*)ws)[dst_idx] = o;
}

// ---------------------------------------------------------------------------
// k_g1: GEMM1 via MFMA. P[j,b] = sum_k W[j,k] x[b,k]. Split-K NZ1=16.
// One 16x16 tile per wave, 10 MFMA steps of k=32. 1536 blocks.
// ---------------------------------------------------------------------------
__global__ __launch_bounds__(256) void k_g1(char* __restrict__ ws)
{
  const int wid  = blockIdx.x * 4 + (threadIdx.x >> 6);
  const int l    = threadIdx.x & 63;
  const int z    = wid / 384;
  const int rem  = wid - z * 384;
  const int jt   = rem >> 5;
  const int bt   = rem & 31;
  const int j0   = jt * 16, b0 = bt * 16;

  const bf16x8* WPv = (const bf16x8*)(ws + OFF_WP);
  const bf16x8* xPv = (const bf16x8*)(ws + OFF_XP);
  float* part = (float*)(ws + OFF_PART);

  const int lg = l >> 4, lr = l & 15;
  f32x4 acc = {0.f, 0.f, 0.f, 0.f};

#pragma unroll 2
  for (int s = 0; s < 10; ++s) {
    const int k8 = z * 40 + s * 4 + lg;
    const bf16x8 av = WPv[(size_t)k8 * 192 + j0 + lr];
    const bf16x8 bv = xPv[(size_t)k8 * 512 + b0 + lr];
    acc = __builtin_amdgcn_mfma_f32_16x16x32_bf16(av, bv, acc, 0, 0, 0);
  }

  float* pb = part + (size_t)wid * 256;
#pragma unroll
  for (int r = 0; r < 4; ++r)
    pb[(lg * 4 + r) * 16 + lr] = acc[r];
}

// ---------------------------------------------------------------------------
// k_red1: sum 16 slices -> dtrP (bf16 packed) / Bc / Cc. 384 blocks.
// ---------------------------------------------------------------------------
__global__ __launch_bounds__(256) void k_red1(char* __restrict__ ws)
{
  const int e = blockIdx.x * 256 + threadIdx.x;   // (j, b)
  const int j = e >> 9, b = e & 511;
  const int jt = j >> 4, jr = j & 15, bt = b >> 4, bc = b & 15;

  const float* part = (const float*)(ws + OFF_PART);
  float s = 0.f;
#pragma unroll
  for (int z = 0; z < NZ1; ++z)
    s += part[((size_t)(z * 384 + jt * 32 + bt) << 8) + jr * 16 + bc];

  if (j < RK) {
    unsigned short* dtrP = (unsigned short*)(ws + OFF_DTRP);
    dtrP[((size_t)(j >> 3) * 512 + b) * 8 + (j & 7)] = f2bf(s);
  } else if (j < RK + DST) {
    ((float*)(ws + OFF_B))[(size_t)b * DST + (j - RK)] = s;
  } else {
    ((float*)(ws + OFF_C))[(size_t)b * DST + (j - RK - DST)] = s;
  }
}

// ---------------------------------------------------------------------------
// k_g2y: FUSED dt-GEMM + softplus + state update + y.
// One wave per 16b x 16d tile (10240 wave-tasks, 2560 blocks):
//   phase 1: 5-step MFMA -> dt tile -> softplus -> LDS; stage Bc/Cc/x -> LDS.
//   phase 2: fully-unrolled 16-iter loop; only global load is h4 (16B/lane,
//            coalesced 1KB/wave), depth-4 rotating prefetch for ~4 loads in
//            flight per wave. B/C/x/dt come from LDS.
// ---------------------------------------------------------------------------
__global__ __launch_bounds__(256) void k_g2y(
    const float* __restrict__ bdt, const float* __restrict__ A,
    const float* __restrict__ Dp,  const float* __restrict__ x,
    const float* __restrict__ h,   float* __restrict__ y,
    char* __restrict__ ws)
{
  __shared__ float sDT[4][16][17];
  __shared__ float sB[4][16][16];
  __shared__ float sC[4][16][16];
  __shared__ float sX[4][16][16];

  const int w = threadIdx.x >> 6;
  const int l = threadIdx.x & 63;
  const int wid = blockIdx.x * 4 + w;
  const int dtile = wid % 320, btile = wid / 320;
  const int d0 = dtile * 16, b0 = btile * 16;

  const bf16x8* dtrPv = (const bf16x8*)(ws + OFF_DTRP);
  const bf16x8* WdtPv = (const bf16x8*)(ws + OFF_WDTP);
  const float*  Bc    = (const float*)(ws + OFF_B);
  const float*  Cc    = (const float*)(ws + OFF_C);

  // ---- stage Bc/Cc (contiguous 256 floats each) and x tile into LDS ----
  *(float4*)&((float*)sB[w])[l * 4] = *(const float4*)&Bc[b0 * DST + l * 4];
  *(float4*)&((float*)sC[w])[l * 4] = *(const float4*)&Cc[b0 * DST + l * 4];
  {
    const int xr = l >> 2, xc = (l & 3) * 4;
    *(float4*)&sX[w][xr][xc] = *(const float4*)&x[(size_t)(b0 + xr) * DIN + d0 + xc];
  }

  // ---- phase 1: dt tile via MFMA ----
  const int lg = l >> 4, lr = l & 15;
  f32x4 acc = {0.f, 0.f, 0.f, 0.f};
#pragma unroll
  for (int s = 0; s < 5; ++s) {
    const int k8 = s * 4 + lg;
    const bf16x8 av = dtrPv[(size_t)k8 * 512 + b0 + lr];
    const bf16x8 bv = WdtPv[(size_t)k8 * 5120 + d0 + lr];
    acc = __builtin_amdgcn_mfma_f32_16x16x32_bf16(av, bv, acc, 0, 0, 0);
  }
  const float bias = bdt[d0 + lr];
#pragma unroll
  for (int r = 0; r < 4; ++r) {
    const float pre = acc[r] + bias;   // dt for (b=b0+lg*4+r, d=d0+lr)
    sDT[w][lg * 4 + r][lr] = (pre > 20.f) ? pre : log1pf(__expf(pre));
  }
  __syncthreads();

  // ---- phase 2: pipelined h-streaming ----
  const int q = l & 3;      // state group (4 states)
  const int Q = l >> 2;     // d offset within tile
  const int d = d0 + Q;
  const float4 A4 = *(const float4*)(A + (size_t)d * DST + q * 4);
  const float  Dv = Dp[d];

  const float* hp = h + ((size_t)b0 * DIN + d) * DST + q * 4;   // j-th: + j*DIN*DST
  float* yp = y + (size_t)b0 * DIN + d;

  float4 hbuf[4];
#pragma unroll
  for (int j = 0; j < 4; ++j)
    hbuf[j] = *(const float4*)(hp + (size_t)j * (DIN * DST));

#pragma unroll
  for (int j = 0; j < 16; ++j) {
    const float4 h4 = hbuf[j & 3];
    if (j + 4 < 16)
      hbuf[j & 3] = *(const float4*)(hp + (size_t)(j + 4) * (DIN * DST));

    const float dtv = sDT[w][j][Q];
    const float xv  = sX[w][j][Q];
    const float dtx = dtv * xv;
    const float4 B4 = *(const float4*)&sB[w][j][q * 4];
    const float4 C4 = *(const float4*)&sC[w][j][q * 4];

    const float dA0 = __expf(A4.x * dtv);
    const float dA1 = __expf(A4.y * dtv);
    const float dA2 = __expf(A4.z * dtv);
    const float dA3 = __expf(A4.w * dtv);
    const float hn0 = fmaf(dA0, h4.x, dtx * B4.x);
    const float hn1 = fmaf(dA1, h4.y, dtx * B4.y);
    const float hn2 = fmaf(dA2, h4.z, dtx * B4.z);
    const float hn3 = fmaf(dA3, h4.w, dtx * B4.w);
    float p = hn0 * C4.x + hn1 * C4.y + hn2 * C4.z + hn3 * C4.w;

    p += __shfl_xor(p, 1);
    p += __shfl_xor(p, 2);
    if (q == 0) yp[(size_t)j * DIN] = fmaf(Dv, xv, p);
  }
}

extern "C" void kernel_launch(void* const* d_in, const int* in_sizes, int n_in,
                              void* d_out, int out_size, void* d_ws, size_t ws_size,
                              hipStream_t stream) {
  const float* x    = (const float*)d_in[0];
  const float* Wdtr = (const float*)d_in[1];
  const float* Wdt  = (const float*)d_in[2];
  const float* bdt  = (const float*)d_in[3];
  const float* WB   = (const float*)d_in[4];
  const float* WC   = (const float*)d_in[5];
  const float* A    = (const float*)d_in[6];
  const float* Dp   = (const float*)d_in[7];
  const float* h    = (const float*)d_in[8];
  float* y = (float*)d_out;
  char* ws = (char*)d_ws;

  k_prep<<<dim3(2160), 256, 0, stream>>>(x, Wdtr, WB, WC, Wdt, ws);
  k_g1<<<dim3(1536), 256, 0, stream>>>(ws);
  k_red1<<<dim3(384), 256, 0, stream>>>(ws);
  k_g2y<<<dim3(2560), 256, 0, stream>>>(bdt, A, Dp, x, h, y, ws);
}